// Round 2
// baseline (455.207 us; speedup 1.0000x reference)
//
#include <hip/hip_runtime.h>
#include <hip/hip_fp16.h>

#define B_SZ  512
#define S_LEN 512
#define D_IN  64
#define H_DIM 32

// fast sigmoid / tanh via v_exp_f32 (base-2) + v_rcp_f32.
__device__ __forceinline__ float fsig(float x) {
    float e = __builtin_amdgcn_exp2f(x * -1.44269504088896340736f);
    return __builtin_amdgcn_rcpf(1.0f + e);
}
__device__ __forceinline__ float ftanh(float x) {
    float e = __builtin_amdgcn_exp2f(x * -2.88539008177792681472f);
    return __builtin_fmaf(2.0f, __builtin_amdgcn_rcpf(1.0f + e), -1.0f);
}

// ---------------------------------------------------------------------------
// Kernel 1: gx[row][n] = sum_k x[row][k]*Wih0[n][k] + bih0[n] + bhh0[n]
// Output PERMUTED fp16: gx2[row][l] = half2( col l , col l+64 ), l in [0,64).
// (scan lane l consumes exactly gx2[row][l] as one dword.)
// Block: 256 threads, 64 rows x 128 cols per block. Grid: 4096.
// ---------------------------------------------------------------------------
__global__ __launch_bounds__(256) void xproj_kernel(
    const float* __restrict__ x,
    const float* __restrict__ Wih0,
    const float* __restrict__ bih0,
    const float* __restrict__ bhh0,
    __half* __restrict__ gxh)
{
    __shared__ float xs[64][66];
    __shared__ float wt[64][132];   // Wih0 transposed

    const int tid = threadIdx.x;
    const size_t row0 = (size_t)blockIdx.x * 64;

    // stage Wih0^T : Wih0 is [128][64] = 2048 float4
    #pragma unroll
    for (int i = 0; i < 8; ++i) {
        int f4 = tid + i * 256;
        int n  = f4 >> 4;
        int k4 = (f4 & 15) << 2;
        float4 v = reinterpret_cast<const float4*>(Wih0)[f4];
        wt[k4 + 0][n] = v.x;
        wt[k4 + 1][n] = v.y;
        wt[k4 + 2][n] = v.z;
        wt[k4 + 3][n] = v.w;
    }
    // stage 64 rows of x : 1024 float4
    #pragma unroll
    for (int i = 0; i < 4; ++i) {
        int f4 = tid + i * 256;
        int r  = f4 >> 4;
        int k4 = (f4 & 15) << 2;
        float4 v = reinterpret_cast<const float4*>(x + row0 * D_IN)[f4];
        xs[r][k4 + 0] = v.x;
        xs[r][k4 + 1] = v.y;
        xs[r][k4 + 2] = v.z;
        xs[r][k4 + 3] = v.w;
    }
    __syncthreads();

    const int cg = tid & 15;    // 16 col groups
    const int rg = tid >> 4;    // 16 row groups * 4 rows
    const int n0 = cg << 2;     // base cols n0..n0+3 and n0+64..n0+67
    const int r0 = rg << 2;

    // acc[r][c]: c<4 -> col n0+c ; c>=4 -> col n0+64+(c-4)
    float acc[4][8];
    #pragma unroll
    for (int c = 0; c < 8; ++c) {
        int col = n0 + (c & 3) + ((c >> 2) << 6);
        float bb = bih0[col] + bhh0[col];
        #pragma unroll
        for (int r = 0; r < 4; ++r) acc[r][c] = bb;
    }

    #pragma unroll 4
    for (int k = 0; k < 64; ++k) {
        const float4 wa = *reinterpret_cast<const float4*>(&wt[k][n0]);
        const float4 wb = *reinterpret_cast<const float4*>(&wt[k][n0 + 64]);
        float wv[8] = {wa.x, wa.y, wa.z, wa.w, wb.x, wb.y, wb.z, wb.w};
        float xv[4];
        #pragma unroll
        for (int r = 0; r < 4; ++r) xv[r] = xs[r0 + r][k];
        #pragma unroll
        for (int r = 0; r < 4; ++r)
            #pragma unroll
            for (int c = 0; c < 8; ++c)
                acc[r][c] = __builtin_fmaf(xv[r], wv[c], acc[r][c]);
    }

    #pragma unroll
    for (int r = 0; r < 4; ++r) {
        size_t row = row0 + r0 + r;
        float4 pack;
        __half2* h2 = reinterpret_cast<__half2*>(&pack);
        #pragma unroll
        for (int q = 0; q < 4; ++q) {
            __half2 p;
            p.x = __float2half_rn(acc[r][q]);       // col n0+q
            p.y = __float2half_rn(acc[r][4 + q]);   // col n0+64+q
            h2[q] = p;
        }
        // half index row*128 + 2*n0 ; byte offset row*256 + 4*n0 (16B aligned)
        *reinterpret_cast<float4*>(gxh + row * 128 + 2 * n0) = pack;
    }
}

// ---------------------------------------------------------------------------
// Kernel 2: fused 2-layer LSTM scan + FC epilogue. ONE WAVE PER BATCH ROW.
// Lane l owns gate rows rA=l and rB=l+64.
//   rA: l<32 -> i_l (sig), l>=32 -> f_{l-32} (sig)      [always sigmoid]
//   rB: l<32 -> g_l (tanh), l>=32 -> o_{l-32} (sig)     [branchless constants]
// No __syncthreads: gate combine via 2x shfl_xor(32); h broadcast via
// in-wave LDS write + uniform float4 reads.
// ---------------------------------------------------------------------------
__global__ __launch_bounds__(64, 1) void lstm_scan_kernel(
    const __half2* __restrict__ gx2,   // [B*S][64] permuted pairs
    const float* __restrict__ Whh0,
    const float* __restrict__ Wih1,
    const float* __restrict__ Whh1,
    const float* __restrict__ bih1,
    const float* __restrict__ bhh1,
    const float* __restrict__ Wfc,
    const float* __restrict__ bfc,
    float* __restrict__ out)
{
    const int lane = threadIdx.x;
    const int b    = blockIdx.x;
    const int rA   = lane;
    const int rB   = lane + 64;
    const bool lo  = (lane < 32);

    __shared__ float h0s[32];
    __shared__ float h1s[32];

    float w0a[32], w0b[32], wi1a[32], wi1b[32], wh1a[32], wh1b[32];
    #pragma unroll
    for (int k4 = 0; k4 < 8; ++k4) {
        float4 v;
        v = reinterpret_cast<const float4*>(Whh0 + rA * 32)[k4];
        w0a[4*k4+0]=v.x; w0a[4*k4+1]=v.y; w0a[4*k4+2]=v.z; w0a[4*k4+3]=v.w;
        v = reinterpret_cast<const float4*>(Whh0 + rB * 32)[k4];
        w0b[4*k4+0]=v.x; w0b[4*k4+1]=v.y; w0b[4*k4+2]=v.z; w0b[4*k4+3]=v.w;
        v = reinterpret_cast<const float4*>(Wih1 + rA * 32)[k4];
        wi1a[4*k4+0]=v.x; wi1a[4*k4+1]=v.y; wi1a[4*k4+2]=v.z; wi1a[4*k4+3]=v.w;
        v = reinterpret_cast<const float4*>(Wih1 + rB * 32)[k4];
        wi1b[4*k4+0]=v.x; wi1b[4*k4+1]=v.y; wi1b[4*k4+2]=v.z; wi1b[4*k4+3]=v.w;
        v = reinterpret_cast<const float4*>(Whh1 + rA * 32)[k4];
        wh1a[4*k4+0]=v.x; wh1a[4*k4+1]=v.y; wh1a[4*k4+2]=v.z; wh1a[4*k4+3]=v.w;
        v = reinterpret_cast<const float4*>(Whh1 + rB * 32)[k4];
        wh1b[4*k4+0]=v.x; wh1b[4*k4+1]=v.y; wh1b[4*k4+2]=v.z; wh1b[4*k4+3]=v.w;
    }
    const float b1a = bih1[rA] + bhh1[rA];
    const float b1b = bih1[rB] + bhh1[rB];

    // branchless act-B constants: lanes<32 tanh, lanes>=32 sigmoid
    const float sclB = lo ? -2.88539008177792681472f : -1.44269504088896340736f;
    const float mulB = lo ?  2.0f : 1.0f;
    const float addB = lo ? -1.0f : 0.0f;

    float h0v[32], h1v[32];
    #pragma unroll
    for (int k = 0; k < 32; ++k) { h0v[k] = 0.f; h1v[k] = 0.f; }
    float c0 = 0.f, c1 = 0.f;

    const __half2* gp = gx2 + (size_t)b * S_LEN * 64 + lane;
    __half2 gc = gp[0];

    for (int t = 0; t < S_LEN; ++t) {
        __half2 gn = gc;
        if (t + 1 < S_LEN) gn = gp[(size_t)(t + 1) * 64];

        const float ga = __half2float(gc.x);
        const float gb = __half2float(gc.y);

        // ---- layer 0 gate dots (uses h0v = h0(t-1), in regs)
        float ra0 = ga, ra1 = 0.f, ra2 = 0.f, ra3 = 0.f;
        float rb0 = gb, rb1 = 0.f, rb2 = 0.f, rb3 = 0.f;
        #pragma unroll
        for (int k = 0; k < 32; k += 4) {
            ra0 = __builtin_fmaf(h0v[k+0], w0a[k+0], ra0);
            ra1 = __builtin_fmaf(h0v[k+1], w0a[k+1], ra1);
            ra2 = __builtin_fmaf(h0v[k+2], w0a[k+2], ra2);
            ra3 = __builtin_fmaf(h0v[k+3], w0a[k+3], ra3);
            rb0 = __builtin_fmaf(h0v[k+0], w0b[k+0], rb0);
            rb1 = __builtin_fmaf(h0v[k+1], w0b[k+1], rb1);
            rb2 = __builtin_fmaf(h0v[k+2], w0b[k+2], rb2);
            rb3 = __builtin_fmaf(h0v[k+3], w0b[k+3], rb3);
        }
        const float ra = (ra0 + ra1) + (ra2 + ra3);
        const float rb = (rb0 + rb1) + (rb2 + rb3);

        // ---- layer 1 recurrent part (independent of layer-0 chain; fills
        //      the act0 latency and the h0 LDS round-trip)
        float qa0 = b1a, qa1 = 0.f, qa2 = 0.f, qa3 = 0.f;
        float qb0 = b1b, qb1 = 0.f, qb2 = 0.f, qb3 = 0.f;
        #pragma unroll
        for (int k = 0; k < 32; k += 4) {
            qa0 = __builtin_fmaf(h1v[k+0], wh1a[k+0], qa0);
            qa1 = __builtin_fmaf(h1v[k+1], wh1a[k+1], qa1);
            qa2 = __builtin_fmaf(h1v[k+2], wh1a[k+2], qa2);
            qa3 = __builtin_fmaf(h1v[k+3], wh1a[k+3], qa3);
            qb0 = __builtin_fmaf(h1v[k+0], wh1b[k+0], qb0);
            qb1 = __builtin_fmaf(h1v[k+1], wh1b[k+1], qb1);
            qb2 = __builtin_fmaf(h1v[k+2], wh1b[k+2], qb2);
            qb3 = __builtin_fmaf(h1v[k+3], wh1b[k+3], qb3);
        }

        // ---- layer 0 activations + combine (i,f,g,o) via shfl_xor(32)
        const float va = fsig(ra);                       // rows l : sigmoid
        float vb;
        { float e = __builtin_amdgcn_exp2f(sclB * rb);
          vb = __builtin_fmaf(mulB, __builtin_amdgcn_rcpf(1.0f + e), addB); }
        const float sva = __shfl_xor(va, 32);
        const float svb = __shfl_xor(vb, 32);
        const float iv = lo ? va  : sva;
        const float fv = lo ? sva : va;
        const float gv = lo ? vb  : svb;
        const float ov = lo ? svb : vb;
        c0 = __builtin_fmaf(fv, c0, iv * gv);            // replicated both halves
        const float h0 = ov * ftanh(c0);
        if (lo) h0s[lane] = h0;

        // broadcast h0(t): uniform-address reads, no bank conflicts
        #pragma unroll
        for (int k4 = 0; k4 < 8; ++k4) {
            float4 v = reinterpret_cast<const float4*>(h0s)[k4];
            h0v[4*k4+0]=v.x; h0v[4*k4+1]=v.y; h0v[4*k4+2]=v.z; h0v[4*k4+3]=v.w;
        }

        // ---- layer 1 input part
        #pragma unroll
        for (int k = 0; k < 32; k += 4) {
            qa0 = __builtin_fmaf(h0v[k+0], wi1a[k+0], qa0);
            qa1 = __builtin_fmaf(h0v[k+1], wi1a[k+1], qa1);
            qa2 = __builtin_fmaf(h0v[k+2], wi1a[k+2], qa2);
            qa3 = __builtin_fmaf(h0v[k+3], wi1a[k+3], qa3);
            qb0 = __builtin_fmaf(h0v[k+0], wi1b[k+0], qb0);
            qb1 = __builtin_fmaf(h0v[k+1], wi1b[k+1], qb1);
            qb2 = __builtin_fmaf(h0v[k+2], wi1b[k+2], qb2);
            qb3 = __builtin_fmaf(h0v[k+3], wi1b[k+3], qb3);
        }
        const float qa = (qa0 + qa1) + (qa2 + qa3);
        const float qb = (qb0 + qb1) + (qb2 + qb3);

        // ---- layer 1 activations + combine
        const float wa1 = fsig(qa);
        float wb1;
        { float e = __builtin_amdgcn_exp2f(sclB * qb);
          wb1 = __builtin_fmaf(mulB, __builtin_amdgcn_rcpf(1.0f + e), addB); }
        const float swa = __shfl_xor(wa1, 32);
        const float swb = __shfl_xor(wb1, 32);
        const float iv1 = lo ? wa1 : swa;
        const float fv1 = lo ? swa : wa1;
        const float gv1 = lo ? wb1 : swb;
        const float ov1 = lo ? swb : wb1;
        c1 = __builtin_fmaf(fv1, c1, iv1 * gv1);
        const float h1 = ov1 * ftanh(c1);
        if (lo) h1s[lane] = h1;

        // broadcast h1(t) (round-trip covered by next iter's layer-0 dots)
        #pragma unroll
        for (int k4 = 0; k4 < 8; ++k4) {
            float4 v = reinterpret_cast<const float4*>(h1s)[k4];
            h1v[4*k4+0]=v.x; h1v[4*k4+1]=v.y; h1v[4*k4+2]=v.z; h1v[4*k4+3]=v.w;
        }

        gc = gn;
    }

    // FC epilogue: every lane holds full h1v; lane 0 writes
    if (lane == 0) {
        float s = bfc[0];
        #pragma unroll
        for (int k = 0; k < 32; ++k) s = __builtin_fmaf(h1v[k], Wfc[k], s);
        out[b] = s;
    }
}

extern "C" void kernel_launch(void* const* d_in, const int* in_sizes, int n_in,
                              void* d_out, int out_size, void* d_ws, size_t ws_size,
                              hipStream_t stream) {
    (void)in_sizes; (void)n_in; (void)out_size;
    const float* x    = (const float*)d_in[0];
    const float* Wih0 = (const float*)d_in[1];
    const float* Whh0 = (const float*)d_in[2];
    const float* bih0 = (const float*)d_in[3];
    const float* bhh0 = (const float*)d_in[4];
    const float* Wih1 = (const float*)d_in[5];
    const float* Whh1 = (const float*)d_in[6];
    const float* bih1 = (const float*)d_in[7];
    const float* bhh1 = (const float*)d_in[8];
    const float* Wfc  = (const float*)d_in[9];
    const float* bfc  = (const float*)d_in[10];
    float* out = (float*)d_out;

    const size_t need = (size_t)B_SZ * S_LEN * 128 * sizeof(__half);  // 64 MB
    if (ws_size < need) return;
    __half* gxh = (__half*)d_ws;

    hipLaunchKernelGGL(xproj_kernel, dim3((B_SZ * S_LEN) / 64), dim3(256), 0, stream,
                       x, Wih0, bih0, bhh0, gxh);
    hipLaunchKernelGGL(lstm_scan_kernel, dim3(B_SZ), dim3(64), 0, stream,
                       (const __half2*)gxh, Whh0, Wih1, Whh1, bih1, bhh1, Wfc, bfc, out);
}

// Round 3
// 368.384 us; speedup vs baseline: 1.2357x; 1.2357x over previous
//
#include <hip/hip_runtime.h>
#include <hip/hip_fp16.h>

#define B_SZ  512
#define S_LEN 512
#define D_IN  64
#define H_DIM 32

typedef _Float16 h2 __attribute__((ext_vector_type(2)));

// fast sigmoid / tanh via v_exp_f32 (base-2) + v_rcp_f32.
__device__ __forceinline__ float fsig(float x) {
    float e = __builtin_amdgcn_exp2f(x * -1.44269504088896340736f);
    return __builtin_amdgcn_rcpf(1.0f + e);
}
__device__ __forceinline__ float ftanh(float x) {
    float e = __builtin_amdgcn_exp2f(x * -2.88539008177792681472f);
    return __builtin_fmaf(2.0f, __builtin_amdgcn_rcpf(1.0f + e), -1.0f);
}

#if __has_builtin(__builtin_amdgcn_fdot2)
__device__ __forceinline__ float fdot2(h2 a, h2 b, float c) {
    return __builtin_amdgcn_fdot2(a, b, c, false);   // v_dot2_f32_f16
}
#else
__device__ __forceinline__ float fdot2(h2 a, h2 b, float c) {
    return __builtin_fmaf((float)a[1], (float)b[1],
           __builtin_fmaf((float)a[0], (float)b[0], c));
}
#endif

__device__ __forceinline__ h2 u2h2(unsigned int u) { return __builtin_bit_cast(h2, u); }

// ---------------------------------------------------------------------------
// Kernel 1: gx[row][n] = sum_k x[row][k]*Wih0[n][k] + bih0[n] + bhh0[n]
// Output fp16, LANE LAYOUT for scan: gxh[row*128 + j*4 + g] = col (g*32 + j).
// Block: 256 threads, 64 rows x 128 cols per block. Grid: 4096.
// ---------------------------------------------------------------------------
__global__ __launch_bounds__(256) void xproj_kernel(
    const float* __restrict__ x,
    const float* __restrict__ Wih0,
    const float* __restrict__ bih0,
    const float* __restrict__ bhh0,
    unsigned short* __restrict__ gxh)
{
    __shared__ float xs[64][66];
    __shared__ float wt[64][132];   // Wih0 transposed: wt[k][n]

    const int tid = threadIdx.x;
    const size_t row0 = (size_t)blockIdx.x * 64;

    // stage Wih0^T : Wih0 is [128][64] = 2048 float4
    #pragma unroll
    for (int i = 0; i < 8; ++i) {
        int f4 = tid + i * 256;
        int n  = f4 >> 4;
        int k4 = (f4 & 15) << 2;
        float4 v = reinterpret_cast<const float4*>(Wih0)[f4];
        wt[k4 + 0][n] = v.x;
        wt[k4 + 1][n] = v.y;
        wt[k4 + 2][n] = v.z;
        wt[k4 + 3][n] = v.w;
    }
    // stage 64 rows of x : 1024 float4
    #pragma unroll
    for (int i = 0; i < 4; ++i) {
        int f4 = tid + i * 256;
        int r  = f4 >> 4;
        int k4 = (f4 & 15) << 2;
        float4 v = reinterpret_cast<const float4*>(x + row0 * D_IN)[f4];
        xs[r][k4 + 0] = v.x;
        xs[r][k4 + 1] = v.y;
        xs[r][k4 + 2] = v.z;
        xs[r][k4 + 3] = v.w;
    }
    __syncthreads();

    const int cg = tid & 15;    // owns j0 = 2cg, 2cg+1 across all 4 gates
    const int rg = tid >> 4;    // 16 row groups * 4 rows
    const int j0 = cg << 1;
    const int r0 = rg << 2;

    // acc[r][g*2+q] -> col g*32 + j0 + q
    float acc[4][8];
    #pragma unroll
    for (int g = 0; g < 4; ++g)
        #pragma unroll
        for (int q = 0; q < 2; ++q) {
            int col = g * 32 + j0 + q;
            float bb = bih0[col] + bhh0[col];
            #pragma unroll
            for (int r = 0; r < 4; ++r) acc[r][g * 2 + q] = bb;
        }

    #pragma unroll 4
    for (int k = 0; k < 64; ++k) {
        float wv[8];
        #pragma unroll
        for (int g = 0; g < 4; ++g) {
            float2 w = *reinterpret_cast<const float2*>(&wt[k][g * 32 + j0]);
            wv[2 * g + 0] = w.x;
            wv[2 * g + 1] = w.y;
        }
        float xv[4];
        #pragma unroll
        for (int r = 0; r < 4; ++r) xv[r] = xs[r0 + r][k];
        #pragma unroll
        for (int r = 0; r < 4; ++r)
            #pragma unroll
            for (int c = 0; c < 8; ++c)
                acc[r][c] = __builtin_fmaf(xv[r], wv[c], acc[r][c]);
    }

    #pragma unroll
    for (int r = 0; r < 4; ++r) {
        size_t row = row0 + r0 + r;
        union { unsigned short s[8]; uint4 v; } pk;
        #pragma unroll
        for (int g = 0; g < 4; ++g)
            #pragma unroll
            for (int q = 0; q < 2; ++q)
                pk.s[q * 4 + g] = __half_as_ushort(__float2half_rn(acc[r][g * 2 + q]));
        *reinterpret_cast<uint4*>(gxh + row * 128 + j0 * 4) = pk.v;
    }
}

// ---------------------------------------------------------------------------
// Kernel 2: fused 2-layer LSTM scan + FC. Half-wave = one batch row.
// Lane = (r = lane>>5, j = lane&31); each lane computes ALL 4 gates for its j
// -> i,f,g,o / c / h fully lane-local (no gate-combine shuffles).
// Dots via v_dot2_f32_f16 (fp16 inputs, fp32 accum). h broadcast via in-wave
// LDS write + uniform uint4 reads (no barriers anywhere).
// ---------------------------------------------------------------------------
__global__ __launch_bounds__(64, 1) void lstm_scan_kernel(
    const unsigned short* __restrict__ gxh,
    const float* __restrict__ Whh0,
    const float* __restrict__ Wih1,
    const float* __restrict__ Whh1,
    const float* __restrict__ bih1,
    const float* __restrict__ bhh1,
    const float* __restrict__ Wfc,
    const float* __restrict__ bfc,
    float* __restrict__ out)
{
    const int lane = threadIdx.x;
    const int j    = lane & 31;
    const int r    = lane >> 5;
    const int row  = (blockIdx.x << 1) | r;

    __shared__ unsigned short h0sm[2][32];   // [r][j] fp16 bits
    __shared__ unsigned short h1sm[2][32];

    // per-lane weights: rows g*32+j of Whh0 / Wih1 / Whh1, packed half2
    h2 wh0[4][16], wi1[4][16], wh1[4][16];
    float b1[4];
    #pragma unroll
    for (int g = 0; g < 4; ++g) {
        const float4* p0 = reinterpret_cast<const float4*>(Whh0 + (g * 32 + j) * 32);
        const float4* p1 = reinterpret_cast<const float4*>(Wih1 + (g * 32 + j) * 32);
        const float4* p2 = reinterpret_cast<const float4*>(Whh1 + (g * 32 + j) * 32);
        #pragma unroll
        for (int k4 = 0; k4 < 8; ++k4) {
            float4 v;
            v = p0[k4];
            wh0[g][2*k4+0] = (h2){(_Float16)v.x, (_Float16)v.y};
            wh0[g][2*k4+1] = (h2){(_Float16)v.z, (_Float16)v.w};
            v = p1[k4];
            wi1[g][2*k4+0] = (h2){(_Float16)v.x, (_Float16)v.y};
            wi1[g][2*k4+1] = (h2){(_Float16)v.z, (_Float16)v.w};
            v = p2[k4];
            wh1[g][2*k4+0] = (h2){(_Float16)v.x, (_Float16)v.y};
            wh1[g][2*k4+1] = (h2){(_Float16)v.z, (_Float16)v.w};
        }
        b1[g] = bih1[g * 32 + j] + bhh1[g * 32 + j];
    }

    h2 h0p[16], h1p[16];
    #pragma unroll
    for (int k = 0; k < 16; ++k) { h0p[k] = (h2){0, 0}; h1p[k] = (h2){0, 0}; }
    float c0 = 0.f, c1 = 0.f;
    float h1last = 0.f;

    // gx: lane reads 4 gate halves at [row][j*4 .. j*4+3] = one uint2 / step
    const uint2* gp = reinterpret_cast<const uint2*>(gxh + (size_t)row * S_LEN * 128) + j;
    uint2 gc = gp[0];

    for (int t = 0; t < S_LEN; ++t) {
        uint2 gn = gc;
        if (t + 1 < S_LEN) gn = gp[(t + 1) * 32];   // prefetch next step

        const h2 g01 = u2h2(gc.x);
        const h2 g23 = u2h2(gc.y);

        // ---- layer 0: 4 gates x dot(h0, Whh0_row)  (8 chains of depth 8)
        float a0 = (float)g01[0], a1 = (float)g01[1];
        float a2 = (float)g23[0], a3 = (float)g23[1];
        float u0 = 0.f, u1 = 0.f, u2 = 0.f, u3 = 0.f;
        #pragma unroll
        for (int k = 0; k < 16; k += 2) {
            a0 = fdot2(h0p[k],   wh0[0][k],   a0);
            a1 = fdot2(h0p[k],   wh0[1][k],   a1);
            a2 = fdot2(h0p[k],   wh0[2][k],   a2);
            a3 = fdot2(h0p[k],   wh0[3][k],   a3);
            u0 = fdot2(h0p[k+1], wh0[0][k+1], u0);
            u1 = fdot2(h0p[k+1], wh0[1][k+1], u1);
            u2 = fdot2(h0p[k+1], wh0[2][k+1], u2);
            u3 = fdot2(h0p[k+1], wh0[3][k+1], u3);
        }
        a0 += u0; a1 += u1; a2 += u2; a3 += u3;

        // ---- layer 1 recurrent part (independent: fills L0's latency chain)
        float q0 = b1[0], q1 = b1[1], q2 = b1[2], q3 = b1[3];
        float s0 = 0.f, s1 = 0.f, s2 = 0.f, s3 = 0.f;
        #pragma unroll
        for (int k = 0; k < 16; k += 2) {
            q0 = fdot2(h1p[k],   wh1[0][k],   q0);
            q1 = fdot2(h1p[k],   wh1[1][k],   q1);
            q2 = fdot2(h1p[k],   wh1[2][k],   q2);
            q3 = fdot2(h1p[k],   wh1[3][k],   q3);
            s0 = fdot2(h1p[k+1], wh1[0][k+1], s0);
            s1 = fdot2(h1p[k+1], wh1[1][k+1], s1);
            s2 = fdot2(h1p[k+1], wh1[2][k+1], s2);
            s3 = fdot2(h1p[k+1], wh1[3][k+1], s3);
        }

        // ---- layer 0 activations, cell, h (all lane-local)
        const float iv = fsig(a0), fv = fsig(a1), gv = ftanh(a2), ov = fsig(a3);
        c0 = __builtin_fmaf(fv, c0, iv * gv);
        const float h0 = ov * ftanh(c0);
        h0sm[r][j] = __half_as_ushort(__float2half_rn(h0));

        // broadcast h0 row (uniform address per half-wave; in-wave lgkm order)
        {
            const uint4* hp = reinterpret_cast<const uint4*>(&h0sm[r][0]);
            uint4 qa = hp[0], qb = hp[1], qc = hp[2], qd = hp[3];
            h0p[ 0]=u2h2(qa.x); h0p[ 1]=u2h2(qa.y); h0p[ 2]=u2h2(qa.z); h0p[ 3]=u2h2(qa.w);
            h0p[ 4]=u2h2(qb.x); h0p[ 5]=u2h2(qb.y); h0p[ 6]=u2h2(qb.z); h0p[ 7]=u2h2(qb.w);
            h0p[ 8]=u2h2(qc.x); h0p[ 9]=u2h2(qc.y); h0p[10]=u2h2(qc.z); h0p[11]=u2h2(qc.w);
            h0p[12]=u2h2(qd.x); h0p[13]=u2h2(qd.y); h0p[14]=u2h2(qd.z); h0p[15]=u2h2(qd.w);
        }

        // ---- layer 1 input part
        #pragma unroll
        for (int k = 0; k < 16; k += 2) {
            q0 = fdot2(h0p[k],   wi1[0][k],   q0);
            q1 = fdot2(h0p[k],   wi1[1][k],   q1);
            q2 = fdot2(h0p[k],   wi1[2][k],   q2);
            q3 = fdot2(h0p[k],   wi1[3][k],   q3);
            s0 = fdot2(h0p[k+1], wi1[0][k+1], s0);
            s1 = fdot2(h0p[k+1], wi1[1][k+1], s1);
            s2 = fdot2(h0p[k+1], wi1[2][k+1], s2);
            s3 = fdot2(h0p[k+1], wi1[3][k+1], s3);
        }
        q0 += s0; q1 += s1; q2 += s2; q3 += s3;

        // ---- layer 1 activations, cell, h
        const float iv1 = fsig(q0), fv1 = fsig(q1), gv1 = ftanh(q2), ov1 = fsig(q3);
        c1 = __builtin_fmaf(fv1, c1, iv1 * gv1);
        const float h1 = ov1 * ftanh(c1);
        h1last = h1;
        h1sm[r][j] = __half_as_ushort(__float2half_rn(h1));

        // broadcast h1 row (latency covered by next iter's L0 dots)
        {
            const uint4* hp = reinterpret_cast<const uint4*>(&h1sm[r][0]);
            uint4 qa = hp[0], qb = hp[1], qc = hp[2], qd = hp[3];
            h1p[ 0]=u2h2(qa.x); h1p[ 1]=u2h2(qa.y); h1p[ 2]=u2h2(qa.z); h1p[ 3]=u2h2(qa.w);
            h1p[ 4]=u2h2(qb.x); h1p[ 5]=u2h2(qb.y); h1p[ 6]=u2h2(qb.z); h1p[ 7]=u2h2(qb.w);
            h1p[ 8]=u2h2(qc.x); h1p[ 9]=u2h2(qc.y); h1p[10]=u2h2(qc.z); h1p[11]=u2h2(qc.w);
            h1p[12]=u2h2(qd.x); h1p[13]=u2h2(qd.y); h1p[14]=u2h2(qd.z); h1p[15]=u2h2(qd.w);
        }

        gc = gn;
    }

    // ---- FC epilogue: fp32 h1 per lane, butterfly reduce within half-wave
    float p = h1last * Wfc[j];
    p += __shfl_xor(p, 16);
    p += __shfl_xor(p, 8);
    p += __shfl_xor(p, 4);
    p += __shfl_xor(p, 2);
    p += __shfl_xor(p, 1);
    if (j == 0) out[row] = p + bfc[0];
}

extern "C" void kernel_launch(void* const* d_in, const int* in_sizes, int n_in,
                              void* d_out, int out_size, void* d_ws, size_t ws_size,
                              hipStream_t stream) {
    (void)in_sizes; (void)n_in; (void)out_size;
    const float* x    = (const float*)d_in[0];
    const float* Wih0 = (const float*)d_in[1];
    const float* Whh0 = (const float*)d_in[2];
    const float* bih0 = (const float*)d_in[3];
    const float* bhh0 = (const float*)d_in[4];
    const float* Wih1 = (const float*)d_in[5];
    const float* Whh1 = (const float*)d_in[6];
    const float* bih1 = (const float*)d_in[7];
    const float* bhh1 = (const float*)d_in[8];
    const float* Wfc  = (const float*)d_in[9];
    const float* bfc  = (const float*)d_in[10];
    float* out = (float*)d_out;

    const size_t need = (size_t)B_SZ * S_LEN * 128 * sizeof(unsigned short);  // 64 MB
    if (ws_size < need) return;
    unsigned short* gxh = (unsigned short*)d_ws;

    hipLaunchKernelGGL(xproj_kernel, dim3((B_SZ * S_LEN) / 64), dim3(256), 0, stream,
                       x, Wih0, bih0, bhh0, gxh);
    hipLaunchKernelGGL(lstm_scan_kernel, dim3(B_SZ / 2), dim3(64), 0, stream,
                       gxh, Whh0, Wih1, Whh1, bih1, bhh1, Wfc, bfc, out);
}

// Round 5
// 312.734 us; speedup vs baseline: 1.4556x; 1.1779x over previous
//
#include <hip/hip_runtime.h>
#include <hip/hip_fp16.h>

#define B_SZ  512
#define S_LEN 512
#define D_IN  64
#define H_DIM 32

typedef _Float16 h2 __attribute__((ext_vector_type(2)));

__device__ __forceinline__ float fsig(float x) {
    float e = __builtin_amdgcn_exp2f(x * -1.44269504088896340736f);
    return __builtin_amdgcn_rcpf(1.0f + e);
}
__device__ __forceinline__ float ftanh(float x) {
    float e = __builtin_amdgcn_exp2f(x * -2.88539008177792681472f);
    return __builtin_fmaf(2.0f, __builtin_amdgcn_rcpf(1.0f + e), -1.0f);
}

#if __has_builtin(__builtin_amdgcn_fdot2)
__device__ __forceinline__ float fdot2(h2 a, h2 b, float c) {
    return __builtin_amdgcn_fdot2(a, b, c, false);   // v_dot2_f32_f16
}
#else
__device__ __forceinline__ float fdot2(h2 a, h2 b, float c) {
    return __builtin_fmaf((float)a[1], (float)b[1],
           __builtin_fmaf((float)a[0], (float)b[0], c));
}
#endif

__device__ __forceinline__ h2 u2h2(unsigned int u) { return __builtin_bit_cast(h2, u); }
__device__ __forceinline__ unsigned int pk16(float x, float y) {
    unsigned int lo = __half_as_ushort(__float2half_rn(x));
    unsigned int hi = __half_as_ushort(__float2half_rn(y));
    return lo | (hi << 16);
}

// Compiler-only memory fence: forbids reordering LDS ops across it without
// emitting any instruction (hardware DS ops are in-order within a wave, and
// it does NOT drain vmcnt, so the gx prefetch stays in flight).
#define LDS_ORDER() asm volatile("" ::: "memory")

// ---------------------------------------------------------------------------
// Kernel 1: gx[row][n] = sum_k x[row][k]*Wih0[n][k] + bih0[n] + bhh0[n]
// Output fp16 u32 lane layout: gxu[row*64 + l] packs for lane l = (gp,j):
//   gp=0 (l<32):  lo = col j      (i),  hi = col 32+j (f)
//   gp=1 (l>=32): lo = col 64+j   (g),  hi = col 96+j (o)
// ---------------------------------------------------------------------------
__global__ __launch_bounds__(256) void xproj_kernel(
    const float* __restrict__ x,
    const float* __restrict__ Wih0,
    const float* __restrict__ bih0,
    const float* __restrict__ bhh0,
    unsigned int* __restrict__ gxu)
{
    __shared__ float xs[64][66];
    __shared__ float wt[64][132];   // Wih0 transposed: wt[k][n]

    const int tid = threadIdx.x;
    const size_t row0 = (size_t)blockIdx.x * 64;

    #pragma unroll
    for (int i = 0; i < 8; ++i) {
        int f4 = tid + i * 256;
        int n  = f4 >> 4;
        int k4 = (f4 & 15) << 2;
        float4 v = reinterpret_cast<const float4*>(Wih0)[f4];
        wt[k4 + 0][n] = v.x;
        wt[k4 + 1][n] = v.y;
        wt[k4 + 2][n] = v.z;
        wt[k4 + 3][n] = v.w;
    }
    #pragma unroll
    for (int i = 0; i < 4; ++i) {
        int f4 = tid + i * 256;
        int r  = f4 >> 4;
        int k4 = (f4 & 15) << 2;
        float4 v = reinterpret_cast<const float4*>(x + row0 * D_IN)[f4];
        xs[r][k4 + 0] = v.x;
        xs[r][k4 + 1] = v.y;
        xs[r][k4 + 2] = v.z;
        xs[r][k4 + 3] = v.w;
    }
    __syncthreads();

    const int cg = tid & 15;
    const int rg = tid >> 4;
    const int j0 = cg << 1;     // j0, j0+1
    const int r0 = rg << 2;

    // acc[r][g*2+q] -> col g*32 + j0 + q
    float acc[4][8];
    #pragma unroll
    for (int g = 0; g < 4; ++g)
        #pragma unroll
        for (int q = 0; q < 2; ++q) {
            int col = g * 32 + j0 + q;
            float bb = bih0[col] + bhh0[col];
            #pragma unroll
            for (int r = 0; r < 4; ++r) acc[r][g * 2 + q] = bb;
        }

    #pragma unroll 4
    for (int k = 0; k < 64; ++k) {
        float wv[8];
        #pragma unroll
        for (int g = 0; g < 4; ++g) {
            float2 w = *reinterpret_cast<const float2*>(&wt[k][g * 32 + j0]);
            wv[2 * g + 0] = w.x;
            wv[2 * g + 1] = w.y;
        }
        float xv[4];
        #pragma unroll
        for (int r = 0; r < 4; ++r) xv[r] = xs[r0 + r][k];
        #pragma unroll
        for (int r = 0; r < 4; ++r)
            #pragma unroll
            for (int c = 0; c < 8; ++c)
                acc[r][c] = __builtin_fmaf(xv[r], wv[c], acc[r][c]);
    }

    #pragma unroll
    for (int r = 0; r < 4; ++r) {
        size_t row = row0 + r0 + r;
        uint2 lo, hi;
        lo.x = pk16(acc[r][0], acc[r][2]);      // j0:   (i, f)
        lo.y = pk16(acc[r][1], acc[r][3]);      // j0+1: (i, f)
        hi.x = pk16(acc[r][4], acc[r][6]);      // j0:   (g, o)
        hi.y = pk16(acc[r][5], acc[r][7]);      // j0+1: (g, o)
        *reinterpret_cast<uint2*>(gxu + row * 64 + j0)      = lo;
        *reinterpret_cast<uint2*>(gxu + row * 64 + 32 + j0) = hi;
    }
}

// ---------------------------------------------------------------------------
// Kernel 2: fused 2-layer LSTM scan + FC. ONE WAVE PER BATCH ROW.
// lane = (gp = lane>>5, j = lane&31); lane owns gate rows (2gp)*32+j and
// (2gp+1)*32+j  ->  per-lane weights = 6 x 16 h2 = 96 VGPRs.
// Gate combine: 2x shfl_xor(32) per layer; c,h replicated in both halves.
// h broadcast: unconditional LDS store (both halves store identical bits)
// sandwiched in compiler memory fences -> no reorder, no vmcnt drain.
// Software-pipelined: next step's L0 dots issue before this step's L1 acts.
// ---------------------------------------------------------------------------
__global__ __launch_bounds__(64, 1) void lstm_scan_kernel(
    const unsigned int* __restrict__ gxu,
    const float* __restrict__ Whh0,
    const float* __restrict__ Wih1,
    const float* __restrict__ Whh1,
    const float* __restrict__ bih1,
    const float* __restrict__ bhh1,
    const float* __restrict__ Wfc,
    const float* __restrict__ bfc,
    float* __restrict__ out)
{
    const int lane = threadIdx.x;
    const int j    = lane & 31;
    const int gp   = lane >> 5;
    const int b    = blockIdx.x;
    const int rA   = gp * 64 + j;        // gate 2gp   row
    const int rB   = rA + 32;            // gate 2gp+1 row

    __shared__ unsigned short h0sm[32];
    __shared__ unsigned short h1sm[32];

    // per-lane weights: 2 gate rows x 3 matrices, packed half2
    h2 wh0A[16], wh0B[16], wi1A[16], wi1B[16], wh1A[16], wh1B[16];
    #pragma unroll
    for (int k4 = 0; k4 < 8; ++k4) {
        float4 v;
        v = reinterpret_cast<const float4*>(Whh0 + rA * 32)[k4];
        wh0A[2*k4+0] = (h2){(_Float16)v.x, (_Float16)v.y};
        wh0A[2*k4+1] = (h2){(_Float16)v.z, (_Float16)v.w};
        v = reinterpret_cast<const float4*>(Whh0 + rB * 32)[k4];
        wh0B[2*k4+0] = (h2){(_Float16)v.x, (_Float16)v.y};
        wh0B[2*k4+1] = (h2){(_Float16)v.z, (_Float16)v.w};
        v = reinterpret_cast<const float4*>(Wih1 + rA * 32)[k4];
        wi1A[2*k4+0] = (h2){(_Float16)v.x, (_Float16)v.y};
        wi1A[2*k4+1] = (h2){(_Float16)v.z, (_Float16)v.w};
        v = reinterpret_cast<const float4*>(Wih1 + rB * 32)[k4];
        wi1B[2*k4+0] = (h2){(_Float16)v.x, (_Float16)v.y};
        wi1B[2*k4+1] = (h2){(_Float16)v.z, (_Float16)v.w};
        v = reinterpret_cast<const float4*>(Whh1 + rA * 32)[k4];
        wh1A[2*k4+0] = (h2){(_Float16)v.x, (_Float16)v.y};
        wh1A[2*k4+1] = (h2){(_Float16)v.z, (_Float16)v.w};
        v = reinterpret_cast<const float4*>(Whh1 + rB * 32)[k4];
        wh1B[2*k4+0] = (h2){(_Float16)v.x, (_Float16)v.y};
        wh1B[2*k4+1] = (h2){(_Float16)v.z, (_Float16)v.w};
    }
    const float b1A = bih1[rA] + bhh1[rA];
    const float b1B = bih1[rB] + bhh1[rB];

    // act-A: gp0 -> sigmoid (i), gp1 -> tanh (g). act-B always sigmoid (f,o).
    const float sclA = gp ? -2.88539008177792681472f : -1.44269504088896340736f;
    const float mulA = gp ?  2.0f : 1.0f;
    const float addA = gp ? -1.0f : 0.0f;

    h2 h0p[16], h1p[16];
    #pragma unroll
    for (int k = 0; k < 16; ++k) { h0p[k] = (h2){0, 0}; h1p[k] = (h2){0, 0}; }
    float c0 = 0.f, c1 = 0.f, h1last = 0.f;

    const unsigned int* gptr = gxu + (size_t)b * S_LEN * 64 + lane;
    h2 gfirst = u2h2(gptr[0]);
    float aA = (float)gfirst[0];   // L0 preact t=0 (h0(-1)=0)
    float aB = (float)gfirst[1];

    for (int t = 0; t < S_LEN; ++t) {
        // prefetch next gx (clamped at the end; value unused for t=511)
        const int tn = (t + 1 < S_LEN) ? (t + 1) : t;
        const unsigned int gn = gptr[(size_t)tn * 64];

        // ---- L1 recurrent dots (independent; fills L0 act latency)
        float qA0 = b1A, qA1 = 0.f, qB0 = b1B, qB1 = 0.f;
        #pragma unroll
        for (int k = 0; k < 16; k += 2) {
            qA0 = fdot2(h1p[k],   wh1A[k],   qA0);
            qA1 = fdot2(h1p[k+1], wh1A[k+1], qA1);
            qB0 = fdot2(h1p[k],   wh1B[k],   qB0);
            qB1 = fdot2(h1p[k+1], wh1B[k+1], qB1);
        }

        // ---- L0 activations + gate combine + cell + h0
        float vA;
        { float e = __builtin_amdgcn_exp2f(sclA * aA);
          vA = __builtin_fmaf(mulA, __builtin_amdgcn_rcpf(1.0f + e), addA); }
        const float vB = fsig(aB);
        const float oA = __shfl_xor(vA, 32);
        const float oB = __shfl_xor(vB, 32);
        const float iv = gp ? oA : vA;
        const float fv = gp ? oB : vB;
        const float gv = gp ? vA : oA;
        const float ov = gp ? vB : oB;
        c0 = __builtin_fmaf(fv, c0, iv * gv);
        const float h0 = ov * ftanh(c0);

        // ---- broadcast h0: unconditional store (both halves identical bits),
        //      fenced so the compiler cannot move LDS ops across it.
        LDS_ORDER();
        h0sm[j] = (unsigned short)__half_as_ushort(__float2half_rn(h0));
        LDS_ORDER();
        {
            const uint4* hp = reinterpret_cast<const uint4*>(h0sm);
            uint4 qa = hp[0], qb = hp[1], qc = hp[2], qd = hp[3];
            h0p[ 0]=u2h2(qa.x); h0p[ 1]=u2h2(qa.y); h0p[ 2]=u2h2(qa.z); h0p[ 3]=u2h2(qa.w);
            h0p[ 4]=u2h2(qb.x); h0p[ 5]=u2h2(qb.y); h0p[ 6]=u2h2(qb.z); h0p[ 7]=u2h2(qb.w);
            h0p[ 8]=u2h2(qc.x); h0p[ 9]=u2h2(qc.y); h0p[10]=u2h2(qc.z); h0p[11]=u2h2(qc.w);
            h0p[12]=u2h2(qd.x); h0p[13]=u2h2(qd.y); h0p[14]=u2h2(qd.z); h0p[15]=u2h2(qd.w);
        }

        // ---- L1 input dots (needs h0p(t))
        #pragma unroll
        for (int k = 0; k < 16; k += 2) {
            qA0 = fdot2(h0p[k],   wi1A[k],   qA0);
            qA1 = fdot2(h0p[k+1], wi1A[k+1], qA1);
            qB0 = fdot2(h0p[k],   wi1B[k],   qB0);
            qB1 = fdot2(h0p[k+1], wi1B[k+1], qB1);
        }

        // ---- NEXT step's L0 dots (needs only h0p(t); independent of L1 acts;
        //      its issue hides the L1 act chain + h1 round-trip)
        h2 gnp = u2h2(gn);
        float zA0 = (float)gnp[0], zA1 = 0.f;
        float zB0 = (float)gnp[1], zB1 = 0.f;
        #pragma unroll
        for (int k = 0; k < 16; k += 2) {
            zA0 = fdot2(h0p[k],   wh0A[k],   zA0);
            zA1 = fdot2(h0p[k+1], wh0A[k+1], zA1);
            zB0 = fdot2(h0p[k],   wh0B[k],   zB0);
            zB1 = fdot2(h0p[k+1], wh0B[k+1], zB1);
        }

        // ---- L1 activations + combine + cell + h1
        const float qA = qA0 + qA1;
        const float qB = qB0 + qB1;
        float wA;
        { float e = __builtin_amdgcn_exp2f(sclA * qA);
          wA = __builtin_fmaf(mulA, __builtin_amdgcn_rcpf(1.0f + e), addA); }
        const float wB = fsig(qB);
        const float pA = __shfl_xor(wA, 32);
        const float pB = __shfl_xor(wB, 32);
        const float iv1 = gp ? pA : wA;
        const float fv1 = gp ? pB : wB;
        const float gv1 = gp ? wA : pA;
        const float ov1 = gp ? wB : pB;
        c1 = __builtin_fmaf(fv1, c1, iv1 * gv1);
        const float h1 = ov1 * ftanh(c1);
        h1last = h1;

        // ---- broadcast h1 (fenced; round-trip hides under next L0 act chain)
        LDS_ORDER();
        h1sm[j] = (unsigned short)__half_as_ushort(__float2half_rn(h1));
        LDS_ORDER();
        {
            const uint4* hp = reinterpret_cast<const uint4*>(h1sm);
            uint4 qa = hp[0], qb = hp[1], qc = hp[2], qd = hp[3];
            h1p[ 0]=u2h2(qa.x); h1p[ 1]=u2h2(qa.y); h1p[ 2]=u2h2(qa.z); h1p[ 3]=u2h2(qa.w);
            h1p[ 4]=u2h2(qb.x); h1p[ 5]=u2h2(qb.y); h1p[ 6]=u2h2(qb.z); h1p[ 7]=u2h2(qb.w);
            h1p[ 8]=u2h2(qc.x); h1p[ 9]=u2h2(qc.y); h1p[10]=u2h2(qc.z); h1p[11]=u2h2(qc.w);
            h1p[12]=u2h2(qd.x); h1p[13]=u2h2(qd.y); h1p[14]=u2h2(qd.z); h1p[15]=u2h2(qd.w);
        }

        aA = (zA0 + zA1);
        aB = (zB0 + zB1);
    }

    // ---- FC epilogue: lanes hold h1(j) (duplicated across halves)
    float p = h1last * Wfc[j];
    p += __shfl_xor(p, 16);
    p += __shfl_xor(p, 8);
    p += __shfl_xor(p, 4);
    p += __shfl_xor(p, 2);
    p += __shfl_xor(p, 1);
    if (lane == 0) out[b] = p + bfc[0];
}

extern "C" void kernel_launch(void* const* d_in, const int* in_sizes, int n_in,
                              void* d_out, int out_size, void* d_ws, size_t ws_size,
                              hipStream_t stream) {
    (void)in_sizes; (void)n_in; (void)out_size;
    const float* x    = (const float*)d_in[0];
    const float* Wih0 = (const float*)d_in[1];
    const float* Whh0 = (const float*)d_in[2];
    const float* bih0 = (const float*)d_in[3];
    const float* bhh0 = (const float*)d_in[4];
    const float* Wih1 = (const float*)d_in[5];
    const float* Whh1 = (const float*)d_in[6];
    const float* bih1 = (const float*)d_in[7];
    const float* bhh1 = (const float*)d_in[8];
    const float* Wfc  = (const float*)d_in[9];
    const float* bfc  = (const float*)d_in[10];
    float* out = (float*)d_out;

    const size_t need = (size_t)B_SZ * S_LEN * 64 * sizeof(unsigned int);  // 64 MB
    if (ws_size < need) return;
    unsigned int* gxu = (unsigned int*)d_ws;

    hipLaunchKernelGGL(xproj_kernel, dim3((B_SZ * S_LEN) / 64), dim3(256), 0, stream,
                       x, Wih0, bih0, bhh0, gxu);
    hipLaunchKernelGGL(lstm_scan_kernel, dim3(B_SZ), dim3(64), 0, stream,
                       gxu, Whh0, Wih1, Whh1, bih1, bhh1, Wfc, bfc, out);
}

// Round 6
// 295.518 us; speedup vs baseline: 1.5404x; 1.0583x over previous
//
#include <hip/hip_runtime.h>
#include <hip/hip_fp16.h>

#define B_SZ  512
#define S_LEN 512
#define D_IN  64
#define H_DIM 32

typedef _Float16 h2 __attribute__((ext_vector_type(2)));

__device__ __forceinline__ float fsig(float x) {
    float e = __builtin_amdgcn_exp2f(x * -1.44269504088896340736f);
    return __builtin_amdgcn_rcpf(1.0f + e);
}
__device__ __forceinline__ float ftanh(float x) {
    float e = __builtin_amdgcn_exp2f(x * -2.88539008177792681472f);
    return __builtin_fmaf(2.0f, __builtin_amdgcn_rcpf(1.0f + e), -1.0f);
}

#if __has_builtin(__builtin_amdgcn_fdot2)
__device__ __forceinline__ float fdot2(h2 a, h2 b, float c) {
    return __builtin_amdgcn_fdot2(a, b, c, false);   // v_dot2_f32_f16
}
#else
__device__ __forceinline__ float fdot2(h2 a, h2 b, float c) {
    return __builtin_fmaf((float)a[1], (float)b[1],
           __builtin_fmaf((float)a[0], (float)b[0], c));
}
#endif

__device__ __forceinline__ h2 u2h2(unsigned int u) { return __builtin_bit_cast(h2, u); }
__device__ __forceinline__ unsigned int pk16(float x, float y) {
    unsigned int lo = __half_as_ushort(__float2half_rn(x));
    unsigned int hi = __half_as_ushort(__float2half_rn(y));
    return lo | (hi << 16);
}

// Compiler-only memory fence: forbids reordering LDS ops across it without
// emitting any instruction (hardware DS ops are in-order within a wave; does
// NOT drain vmcnt, so global prefetches stay in flight). Correctness-critical
// around the h broadcasts (R4 failed without it).
#define LDS_ORDER() asm volatile("" ::: "memory")

// ---------------------------------------------------------------------------
// Kernel 1: gx[row][n] = sum_k x[row][k]*Wih0[n][k] + bih0[n] + bhh0[n]
// Output fp16 u32 lane layout: gxu[row*64 + l] packs for lane l = (gp,j):
//   gp=0 (l<32):  lo = col j      (i),  hi = col 32+j (f)
//   gp=1 (l>=32): lo = col 64+j   (g),  hi = col 96+j (o)
// ---------------------------------------------------------------------------
__global__ __launch_bounds__(256) void xproj_kernel(
    const float* __restrict__ x,
    const float* __restrict__ Wih0,
    const float* __restrict__ bih0,
    const float* __restrict__ bhh0,
    unsigned int* __restrict__ gxu)
{
    __shared__ float xs[64][66];
    __shared__ float wt[64][132];   // Wih0 transposed: wt[k][n]

    const int tid = threadIdx.x;
    const size_t row0 = (size_t)blockIdx.x * 64;

    #pragma unroll
    for (int i = 0; i < 8; ++i) {
        int f4 = tid + i * 256;
        int n  = f4 >> 4;
        int k4 = (f4 & 15) << 2;
        float4 v = reinterpret_cast<const float4*>(Wih0)[f4];
        wt[k4 + 0][n] = v.x;
        wt[k4 + 1][n] = v.y;
        wt[k4 + 2][n] = v.z;
        wt[k4 + 3][n] = v.w;
    }
    #pragma unroll
    for (int i = 0; i < 4; ++i) {
        int f4 = tid + i * 256;
        int r  = f4 >> 4;
        int k4 = (f4 & 15) << 2;
        float4 v = reinterpret_cast<const float4*>(x + row0 * D_IN)[f4];
        xs[r][k4 + 0] = v.x;
        xs[r][k4 + 1] = v.y;
        xs[r][k4 + 2] = v.z;
        xs[r][k4 + 3] = v.w;
    }
    __syncthreads();

    const int cg = tid & 15;
    const int rg = tid >> 4;
    const int j0 = cg << 1;     // j0, j0+1
    const int r0 = rg << 2;

    // acc[r][g*2+q] -> col g*32 + j0 + q
    float acc[4][8];
    #pragma unroll
    for (int g = 0; g < 4; ++g)
        #pragma unroll
        for (int q = 0; q < 2; ++q) {
            int col = g * 32 + j0 + q;
            float bb = bih0[col] + bhh0[col];
            #pragma unroll
            for (int r = 0; r < 4; ++r) acc[r][g * 2 + q] = bb;
        }

    #pragma unroll 4
    for (int k = 0; k < 64; ++k) {
        float wv[8];
        #pragma unroll
        for (int g = 0; g < 4; ++g) {
            float2 w = *reinterpret_cast<const float2*>(&wt[k][g * 32 + j0]);
            wv[2 * g + 0] = w.x;
            wv[2 * g + 1] = w.y;
        }
        float xv[4];
        #pragma unroll
        for (int r = 0; r < 4; ++r) xv[r] = xs[r0 + r][k];
        #pragma unroll
        for (int r = 0; r < 4; ++r)
            #pragma unroll
            for (int c = 0; c < 8; ++c)
                acc[r][c] = __builtin_fmaf(xv[r], wv[c], acc[r][c]);
    }

    #pragma unroll
    for (int r = 0; r < 4; ++r) {
        size_t row = row0 + r0 + r;
        uint2 lo, hi;
        lo.x = pk16(acc[r][0], acc[r][2]);      // j0:   (i, f)
        lo.y = pk16(acc[r][1], acc[r][3]);      // j0+1: (i, f)
        hi.x = pk16(acc[r][4], acc[r][6]);      // j0:   (g, o)
        hi.y = pk16(acc[r][5], acc[r][7]);      // j0+1: (g, o)
        *reinterpret_cast<uint2*>(gxu + row * 64 + j0)      = lo;
        *reinterpret_cast<uint2*>(gxu + row * 64 + 32 + j0) = hi;
    }
}

// ---------------------------------------------------------------------------
// Kernel 2: fused 2-layer LSTM scan + FC. ONE WAVE PER BATCH ROW.
// lane = (gp = lane>>5, j = lane&31); lane owns gate rows (2gp)*32+j and
// (2gp+1)*32+j -> per-lane weights = 6 x 16 u32 (fp16x2) = 96 VGPRs, PINNED
// register-resident via opaque asm (defeats load rematerialization: R3/R5
// showed VGPR_Count < weight footprint => compiler was reloading in-loop).
// Gate combine: 2x shfl_xor(32) per layer; c,h replicated in both halves.
// h broadcast: unconditional fenced LDS store. 2-deep gx prefetch.
// ---------------------------------------------------------------------------
__global__ __launch_bounds__(64, 1) void lstm_scan_kernel(
    const unsigned int* __restrict__ gxu,
    const float* __restrict__ Whh0,
    const float* __restrict__ Wih1,
    const float* __restrict__ Whh1,
    const float* __restrict__ bih1,
    const float* __restrict__ bhh1,
    const float* __restrict__ Wfc,
    const float* __restrict__ bfc,
    float* __restrict__ out)
{
    const int lane = threadIdx.x;
    const int j    = lane & 31;
    const int gp   = lane >> 5;
    const int b    = blockIdx.x;
    const int rA   = gp * 64 + j;        // gate 2gp   row
    const int rB   = rA + 32;            // gate 2gp+1 row

    __shared__ unsigned short h0sm[32];
    __shared__ unsigned short h1sm[32];

    // per-lane weights: 2 gate rows x 3 matrices, packed fp16 pairs in u32
    unsigned int wh0A[16], wh0B[16], wi1A[16], wi1B[16], wh1A[16], wh1B[16];
    #pragma unroll
    for (int k4 = 0; k4 < 8; ++k4) {
        float4 v;
        v = reinterpret_cast<const float4*>(Whh0 + rA * 32)[k4];
        wh0A[2*k4+0] = pk16(v.x, v.y);  wh0A[2*k4+1] = pk16(v.z, v.w);
        v = reinterpret_cast<const float4*>(Whh0 + rB * 32)[k4];
        wh0B[2*k4+0] = pk16(v.x, v.y);  wh0B[2*k4+1] = pk16(v.z, v.w);
        v = reinterpret_cast<const float4*>(Wih1 + rA * 32)[k4];
        wi1A[2*k4+0] = pk16(v.x, v.y);  wi1A[2*k4+1] = pk16(v.z, v.w);
        v = reinterpret_cast<const float4*>(Wih1 + rB * 32)[k4];
        wi1B[2*k4+0] = pk16(v.x, v.y);  wi1B[2*k4+1] = pk16(v.z, v.w);
        v = reinterpret_cast<const float4*>(Whh1 + rA * 32)[k4];
        wh1A[2*k4+0] = pk16(v.x, v.y);  wh1A[2*k4+1] = pk16(v.z, v.w);
        v = reinterpret_cast<const float4*>(Whh1 + rB * 32)[k4];
        wh1B[2*k4+0] = pk16(v.x, v.y);  wh1B[2*k4+1] = pk16(v.z, v.w);
    }
    // PIN: opaque pass-through; result cannot be rematerialized, so the
    // weights must stay live in VGPRs across the whole scan loop.
    #pragma unroll
    for (int k = 0; k < 16; ++k) {
        asm volatile("" : "+v"(wh0A[k]), "+v"(wh0B[k]),
                          "+v"(wi1A[k]), "+v"(wi1B[k]),
                          "+v"(wh1A[k]), "+v"(wh1B[k]));
    }

    const float b1A = bih1[rA] + bhh1[rA];
    const float b1B = bih1[rB] + bhh1[rB];

    // act-A: gp0 -> sigmoid (i), gp1 -> tanh (g). act-B always sigmoid (f,o).
    const float sclA = gp ? -2.88539008177792681472f : -1.44269504088896340736f;
    const float mulA = gp ?  2.0f : 1.0f;
    const float addA = gp ? -1.0f : 0.0f;

    h2 h0p[16], h1p[16];
    #pragma unroll
    for (int k = 0; k < 16; ++k) { h0p[k] = (h2){0, 0}; h1p[k] = (h2){0, 0}; }
    float c0 = 0.f, c1 = 0.f, h1last = 0.f;

    const unsigned int* gptr = gxu + (size_t)b * S_LEN * 64 + lane;
    h2 gfirst = u2h2(gptr[0]);
    float aA = (float)gfirst[0];   // L0 preact t=0 (h0(-1)=0)
    float aB = (float)gfirst[1];
    unsigned int gnext = gptr[64]; // g(t+1), already in flight

    for (int t = 0; t < S_LEN; ++t) {
        // issue g(t+2) now: a full iteration (~600+ cyc) to cover its latency
        const int tn2 = (t + 2 < S_LEN) ? (t + 2) : (S_LEN - 1);
        const unsigned int gnext2 = gptr[(size_t)tn2 * 64];

        // ---- L1 recurrent dots (independent; fills L0 act latency)
        float qA0 = b1A, qA1 = 0.f, qB0 = b1B, qB1 = 0.f;
        #pragma unroll
        for (int k = 0; k < 16; k += 2) {
            qA0 = fdot2(h1p[k],   u2h2(wh1A[k]),   qA0);
            qA1 = fdot2(h1p[k+1], u2h2(wh1A[k+1]), qA1);
            qB0 = fdot2(h1p[k],   u2h2(wh1B[k]),   qB0);
            qB1 = fdot2(h1p[k+1], u2h2(wh1B[k+1]), qB1);
        }

        // ---- L0 activations + gate combine + cell + h0
        float vA;
        { float e = __builtin_amdgcn_exp2f(sclA * aA);
          vA = __builtin_fmaf(mulA, __builtin_amdgcn_rcpf(1.0f + e), addA); }
        const float vB = fsig(aB);
        const float oA = __shfl_xor(vA, 32);
        const float oB = __shfl_xor(vB, 32);
        const float iv = gp ? oA : vA;
        const float fv = gp ? oB : vB;
        const float gv = gp ? vA : oA;
        const float ov = gp ? vB : oB;
        c0 = __builtin_fmaf(fv, c0, iv * gv);
        const float h0 = ov * ftanh(c0);

        // ---- broadcast h0: unconditional store (both halves identical bits),
        //      fenced so the compiler cannot move LDS ops across it.
        LDS_ORDER();
        h0sm[j] = (unsigned short)__half_as_ushort(__float2half_rn(h0));
        LDS_ORDER();
        {
            const uint4* hp = reinterpret_cast<const uint4*>(h0sm);
            uint4 qa = hp[0], qb = hp[1], qc = hp[2], qd = hp[3];
            h0p[ 0]=u2h2(qa.x); h0p[ 1]=u2h2(qa.y); h0p[ 2]=u2h2(qa.z); h0p[ 3]=u2h2(qa.w);
            h0p[ 4]=u2h2(qb.x); h0p[ 5]=u2h2(qb.y); h0p[ 6]=u2h2(qb.z); h0p[ 7]=u2h2(qb.w);
            h0p[ 8]=u2h2(qc.x); h0p[ 9]=u2h2(qc.y); h0p[10]=u2h2(qc.z); h0p[11]=u2h2(qc.w);
            h0p[12]=u2h2(qd.x); h0p[13]=u2h2(qd.y); h0p[14]=u2h2(qd.z); h0p[15]=u2h2(qd.w);
        }

        // ---- L1 input dots (needs h0p(t))
        #pragma unroll
        for (int k = 0; k < 16; k += 2) {
            qA0 = fdot2(h0p[k],   u2h2(wi1A[k]),   qA0);
            qA1 = fdot2(h0p[k+1], u2h2(wi1A[k+1]), qA1);
            qB0 = fdot2(h0p[k],   u2h2(wi1B[k]),   qB0);
            qB1 = fdot2(h0p[k+1], u2h2(wi1B[k+1]), qB1);
        }

        // ---- NEXT step's L0 dots (needs only h0p(t); independent of L1 acts;
        //      its issue hides the L1 act chain + h1 round-trip)
        h2 gnp = u2h2(gnext);
        float zA0 = (float)gnp[0], zA1 = 0.f;
        float zB0 = (float)gnp[1], zB1 = 0.f;
        #pragma unroll
        for (int k = 0; k < 16; k += 2) {
            zA0 = fdot2(h0p[k],   u2h2(wh0A[k]),   zA0);
            zA1 = fdot2(h0p[k+1], u2h2(wh0A[k+1]), zA1);
            zB0 = fdot2(h0p[k],   u2h2(wh0B[k]),   zB0);
            zB1 = fdot2(h0p[k+1], u2h2(wh0B[k+1]), zB1);
        }

        // ---- L1 activations + combine + cell + h1
        const float qA = qA0 + qA1;
        const float qB = qB0 + qB1;
        float wA;
        { float e = __builtin_amdgcn_exp2f(sclA * qA);
          wA = __builtin_fmaf(mulA, __builtin_amdgcn_rcpf(1.0f + e), addA); }
        const float wB = fsig(qB);
        const float pA = __shfl_xor(wA, 32);
        const float pB = __shfl_xor(wB, 32);
        const float iv1 = gp ? pA : wA;
        const float fv1 = gp ? pB : wB;
        const float gv1 = gp ? wA : pA;
        const float ov1 = gp ? wB : pB;
        c1 = __builtin_fmaf(fv1, c1, iv1 * gv1);
        const float h1 = ov1 * ftanh(c1);
        h1last = h1;

        // ---- broadcast h1 (fenced; round-trip hides under next L0 act chain)
        LDS_ORDER();
        h1sm[j] = (unsigned short)__half_as_ushort(__float2half_rn(h1));
        LDS_ORDER();
        {
            const uint4* hp = reinterpret_cast<const uint4*>(h1sm);
            uint4 qa = hp[0], qb = hp[1], qc = hp[2], qd = hp[3];
            h1p[ 0]=u2h2(qa.x); h1p[ 1]=u2h2(qa.y); h1p[ 2]=u2h2(qa.z); h1p[ 3]=u2h2(qa.w);
            h1p[ 4]=u2h2(qb.x); h1p[ 5]=u2h2(qb.y); h1p[ 6]=u2h2(qb.z); h1p[ 7]=u2h2(qb.w);
            h1p[ 8]=u2h2(qc.x); h1p[ 9]=u2h2(qc.y); h1p[10]=u2h2(qc.z); h1p[11]=u2h2(qc.w);
            h1p[12]=u2h2(qd.x); h1p[13]=u2h2(qd.y); h1p[14]=u2h2(qd.z); h1p[15]=u2h2(qd.w);
        }

        aA = (zA0 + zA1);
        aB = (zB0 + zB1);
        gnext = gnext2;
    }

    // ---- FC epilogue: lanes hold h1(j) (duplicated across halves)
    float p = h1last * Wfc[j];
    p += __shfl_xor(p, 16);
    p += __shfl_xor(p, 8);
    p += __shfl_xor(p, 4);
    p += __shfl_xor(p, 2);
    p += __shfl_xor(p, 1);
    if (lane == 0) out[b] = p + bfc[0];
}

extern "C" void kernel_launch(void* const* d_in, const int* in_sizes, int n_in,
                              void* d_out, int out_size, void* d_ws, size_t ws_size,
                              hipStream_t stream) {
    (void)in_sizes; (void)n_in; (void)out_size;
    const float* x    = (const float*)d_in[0];
    const float* Wih0 = (const float*)d_in[1];
    const float* Whh0 = (const float*)d_in[2];
    const float* bih0 = (const float*)d_in[3];
    const float* bhh0 = (const float*)d_in[4];
    const float* Wih1 = (const float*)d_in[5];
    const float* Whh1 = (const float*)d_in[6];
    const float* bih1 = (const float*)d_in[7];
    const float* bhh1 = (const float*)d_in[8];
    const float* Wfc  = (const float*)d_in[9];
    const float* bfc  = (const float*)d_in[10];
    float* out = (float*)d_out;

    const size_t need = (size_t)B_SZ * S_LEN * 64 * sizeof(unsigned int);  // 64 MB
    if (ws_size < need) return;
    unsigned int* gxu = (unsigned int*)d_ws;

    hipLaunchKernelGGL(xproj_kernel, dim3((B_SZ * S_LEN) / 64), dim3(256), 0, stream,
                       x, Wih0, bih0, bhh0, gxu);
    hipLaunchKernelGGL(lstm_scan_kernel, dim3(B_SZ), dim3(64), 0, stream,
                       gxu, Whh0, Wih1, Whh1, bih1, bhh1, Wfc, bfc, out);
}